// Round 10
// baseline (154.454 us; speedup 1.0000x reference)
//
#include <hip/hip_runtime.h>
#include <hip/hip_bf16.h>

// TripletLoss N=8192, D=128. Round 12: two-dispatch, prep-free structure.
// Round-11 post-mortem: cooperative fusion failed with out=0 signature
// (absmax == ref value, nondeterministic across runs) -- cooperative launch
// under graph capture / grid.sync cross-XCD visibility unverifiable. Revert
// to multi-launch, but cut 4 dispatches -> 2 (each boundary ~13us):
//  - pairs stages B-tiles from RAW f32 F (float4 load, xAK1, cvt_pk bf16,
//    ds_write_b64) computing x2j in-flight via half-wave shuffles; builds
//    A-fragments + x2i from F in-register. No Fb/x2 arrays, no prep.
//  - corr head (by<4 blocks) scans labels itself (LDS-atomic bucket) and
//    computes same-label pair dots in f32 from F (round-6-proven mix:
//    f32 corr vs bf16 main pass cancellation passed absmax 0.0).
//  - gstat zeroed by block (0,0); finalize is the only other dispatch.
// t-units algebra: values scaled by AK1=sqrt2*log2(e) => acc = -AK1^2*d2/2,
// t = sqrt(-acc), exp(-dist) = exp2(-t), dist = t*ln2, pos = exp2(t+C2).

typedef __bf16 bf16x8 __attribute__((ext_vector_type(8)));
typedef float f32x4 __attribute__((ext_vector_type(4)));

#define NROWS 8192
#define DIM 128
#define JTILE 64
#define LDS_STRIDE 136    // 128+8 bf16 pad: 272B rows (odd 16B count -> b128 spread)
#define NLABELS 512
#define GCAP 64           // max rows/label (E=16; P(>64) ~ 1e-30)
#define JSPLIT 16
#define JSPAN (NROWS / JSPLIT)   // 512
#define JITERS (JSPAN / JTILE)   // 8
#define MARGIN_F 0.3f
#define AK1F 2.04027892f      // sqrt2 * log2(e)
#define AK1SQ 4.16273807f     // AK1^2
#define EPS_T 2.08137e-8f     // AK1^2 * 5e-9 (matches reference clip(d2,1e-8))
#define C2F (-43.2808512f)    // -30*log2(e)
#define LN2F 0.69314718f

__device__ __forceinline__ bf16x8 pack8(float4 f0, float4 f1) {
    union { __hip_bfloat162 h[4]; bf16x8 v; } u;
    u.h[0] = __float22bfloat162_rn(make_float2(f0.x, f0.y));
    u.h[1] = __float22bfloat162_rn(make_float2(f0.z, f0.w));
    u.h[2] = __float22bfloat162_rn(make_float2(f1.x, f1.y));
    u.h[3] = __float22bfloat162_rn(make_float2(f1.z, f1.w));
    return u.v;
}

template<bool DIAG>
__device__ __forceinline__ void tile_body(const __hip_bfloat16* __restrict__ sB,
                                          const float* __restrict__ sX2,
                                          const bf16x8 (&a)[4],
                                          const float (&x2ih)[4],
                                          float (&nl4)[4], float (&ns4)[4],
                                          int lm, int quad, int ig0, int jbase) {
#pragma unroll
    for (int jt = 0; jt < 4; ++jt) {
        const int jl = jt * 16 + lm;
        const __hip_bfloat16* bp = sB + jl * LDS_STRIDE + quad * 8;
        const float xj = sX2[jl];
        f32x4 acc;
#pragma unroll
        for (int r = 0; r < 4; ++r) acc[r] = fmaf(-0.5f, xj, x2ih[r]);
#pragma unroll
        for (int kc = 0; kc < 4; ++kc) {
            bf16x8 b = *(const bf16x8*)(bp + kc * 32);
            acc = __builtin_amdgcn_mfma_f32_16x16x32_bf16(a[kc], b, acc, 0, 0, 0);
        }
        const int dj = jbase + jl - ig0;   // self-pair iff dj == r
#pragma unroll
        for (int r = 0; r < 4; ++r) {
            float d2h = fmaxf(-acc[r], EPS_T);        // = AK1^2*d2/2, clipped
            float t = __builtin_amdgcn_sqrtf(d2h);    // dist = t*ln2
            float ne = __builtin_amdgcn_exp2f(-t);    // exp(-dist)
            if (DIAG) ne = (dj == r) ? 0.f : ne;
            nl4[r] += ne;
            ns4[r] = fmaf(ne, t, ns4[r]);
        }
    }
}

__global__ __launch_bounds__(256, 4) void pairs_kernel(
        const float* __restrict__ F,
        const int* __restrict__ labels,
        float2* __restrict__ partial,
        float4* __restrict__ corr,
        float* __restrict__ gstat) {
    __shared__ __hip_bfloat16 sB[JTILE * LDS_STRIDE];
    __shared__ float sX2[JTILE];     // raw scaled x2j
    __shared__ int sIdx[GCAP];
    __shared__ int sCnt;

    const int tid = threadIdx.x;
    const int bx = blockIdx.x, by = blockIdx.y;

    if (bx == 0 && by == 0 && tid < 4) gstat[tid] = 0.f;

    // ---- corr head: 512 blocks (by<4), one label each, before the j-loop --
    if (by < 4) {
        const int L = by * 128 + bx;
        if (tid == 0) sCnt = 0;
        __syncthreads();
        for (int it = 0; it < NROWS / 1024; ++it) {     // 8 iterations
            const int g = it * 1024 + tid * 4;
            int4 lv = *(const int4*)(labels + g);
#pragma unroll
            for (int k = 0; k < 4; ++k) {
                int lab = (k == 0) ? lv.x : (k == 1) ? lv.y : (k == 2) ? lv.z : lv.w;
                if (lab == L) {
                    int pos = atomicAdd(&sCnt, 1);
                    if (pos < GCAP) sIdx[pos] = g + k;
                }
            }
        }
        __syncthreads();
        const int gsz = sCnt < GCAP ? sCnt : GCAP;
        if (gsz > 0) {
            float* sAcc = (float*)sB;          // overlay, pre-staging
            float* plA = sAcc;
            float* psA = sAcc + GCAP;
            float* nlA = sAcc + 2 * GCAP;
            float* nsA = sAcc + 3 * GCAP;
            if (tid < GCAP) { plA[tid] = 0.f; psA[tid] = 0.f; nlA[tid] = 0.f; nsA[tid] = 0.f; }
            __syncthreads();
            const int npair = gsz * gsz;
            for (int p = tid; p < npair; p += 256) {
                const int aI = p / gsz, bI = p - aI * gsz;
                if (aI == bI) continue;
                const float4* pa = (const float4*)(F + (size_t)sIdx[aI] * DIM);
                const float4* pb = (const float4*)(F + (size_t)sIdx[bI] * DIM);
                float dot = 0.f, ssa = 0.f, ssb = 0.f;
#pragma unroll 8
                for (int u = 0; u < 32; ++u) {
                    float4 va = pa[u], vb = pb[u];
                    dot = fmaf(va.x, vb.x, fmaf(va.y, vb.y, fmaf(va.z, vb.z, fmaf(va.w, vb.w, dot))));
                    ssa = fmaf(va.x, va.x, fmaf(va.y, va.y, fmaf(va.z, va.z, fmaf(va.w, va.w, ssa))));
                    ssb = fmaf(vb.x, vb.x, fmaf(vb.y, vb.y, fmaf(vb.z, vb.z, fmaf(vb.w, vb.w, ssb))));
                }
                float d2h = fmaxf((0.5f * (ssa + ssb) - dot) * AK1SQ, EPS_T);
                float t = __builtin_amdgcn_sqrtf(d2h);
                float ne = __builtin_amdgcn_exp2f(-t);
                float pe = __builtin_amdgcn_exp2f(t + C2F);
                unsafeAtomicAdd(&nlA[aI], ne);
                unsafeAtomicAdd(&nsA[aI], ne * t);
                unsafeAtomicAdd(&plA[aI], pe);
                unsafeAtomicAdd(&psA[aI], pe * t);
            }
            __syncthreads();
            if (tid < gsz)
                corr[sIdx[tid]] = make_float4(plA[tid], psA[tid], -nlA[tid], -nsA[tid]);
        }
        __syncthreads();   // corr LDS use done before staging overwrites
    }

    // ---- A-fragments + x2i from raw F (scaled, cvt in-register) ----------
    const int wave = tid >> 6;
    const int lane = tid & 63;
    const int quad = lane >> 4;
    const int lm = lane & 15;
    const int rbase = bx * 64 + wave * 16;

    bf16x8 a[4];
    float ssq = 0.f;
#pragma unroll
    for (int kc = 0; kc < 4; ++kc) {
        const float4* src = (const float4*)(F + (size_t)(rbase + lm) * DIM + kc * 32 + quad * 8);
        float4 f0 = src[0], f1 = src[1];
        f0.x *= AK1F; f0.y *= AK1F; f0.z *= AK1F; f0.w *= AK1F;
        f1.x *= AK1F; f1.y *= AK1F; f1.z *= AK1F; f1.w *= AK1F;
        ssq += f0.x*f0.x + f0.y*f0.y + f0.z*f0.z + f0.w*f0.w
             + f1.x*f1.x + f1.y*f1.y + f1.z*f1.z + f1.w*f1.w;
        a[kc] = pack8(f0, f1);
    }
    ssq += __shfl_xor(ssq, 16, 64);    // combine the 4 quad-chunks of row rbase+lm
    ssq += __shfl_xor(ssq, 32, 64);
    const int ig0 = rbase + quad * 4;
    float x2ih[4];
#pragma unroll
    for (int r = 0; r < 4; ++r)
        x2ih[r] = -0.5f * __shfl(ssq, quad * 4 + r, 64);  // lane lm'=quad*4+r holds that row

    float nl4[4] = {0,0,0,0}, ns4[4] = {0,0,0,0};
    const int j0 = by * JSPAN;
    const int djb = bx - by * JITERS;   // jb holding the diagonal (if in range)

    for (int jb = 0; jb < JITERS; ++jb) {
        const int jbase = j0 + jb * JTILE;
        __syncthreads();   // previous tile's readers done
        // stage 64 rows from raw F: f32x4 chunk c = u*256+tid -> row c>>5,
        // chunk c&31. Half-wave (32 lanes) covers one row per u -> shfl x2.
#pragma unroll
        for (int u = 0; u < 8; ++u) {
            const int c = u * 256 + tid;
            const int jr = c >> 5;
            const int ck = c & 31;
            float4 f = ((const float4*)F)[(size_t)(jbase + jr) * 32 + ck];
            f.x *= AK1F; f.y *= AK1F; f.z *= AK1F; f.w *= AK1F;
            float s4 = f.x*f.x + f.y*f.y + f.z*f.z + f.w*f.w;
#pragma unroll
            for (int m = 1; m <= 16; m <<= 1) s4 += __shfl_xor(s4, m, 64);
            if ((tid & 31) == 0) sX2[jr] = s4;
            union { __hip_bfloat162 h[2]; uint2 u2; } cv;
            cv.h[0] = __float22bfloat162_rn(make_float2(f.x, f.y));
            cv.h[1] = __float22bfloat162_rn(make_float2(f.z, f.w));
            *(uint2*)(sB + jr * LDS_STRIDE + ck * 4) = cv.u2;
        }
        __syncthreads();

        if (jb == djb)
            tile_body<true >(sB, sX2, a, x2ih, nl4, ns4, lm, quad, ig0, jbase);
        else
            tile_body<false>(sB, sX2, a, x2ih, nl4, ns4, lm, quad, ig0, jbase);
    }

    // reduce over the 16 lanes (lm) sharing each i-row
#pragma unroll
    for (int m = 1; m < 16; m <<= 1) {
#pragma unroll
        for (int r = 0; r < 4; ++r) {
            nl4[r] += __shfl_xor(nl4[r], m, 64);
            ns4[r] += __shfl_xor(ns4[r], m, 64);
        }
    }
    if (lm == 0) {
#pragma unroll
        for (int r = 0; r < 4; ++r)
            partial[(size_t)by * NROWS + ig0 + r] = make_float2(nl4[r], ns4[r]);
    }
}

// ---------------- kernel 2: per-row loss, reduce, final divide -------------
__global__ __launch_bounds__(256) void finalize_kernel(const float2* __restrict__ partial,
                                                       const float4* __restrict__ corr,
                                                       float* __restrict__ gstat,
                                                       float* __restrict__ out) {
    const int row = blockIdx.x * 256 + threadIdx.x;
    float4 c = corr[row];
    float nl = c.z, ns = c.w;    // negative corrections (subtract same-label mass)
#pragma unroll
    for (int s = 0; s < JSPLIT; ++s) {
        float2 p = partial[(size_t)s * NROWS + row];
        nl += p.x; ns += p.y;
    }
    float sum = 0.f, cnt = 0.f;
    if (c.x > 0.f && nl > 0.f) {
        float x = fmaf(LN2F, c.y / c.x - ns / nl, MARGIN_F);   // wp - wn + margin
        sum = fmaxf(x, 0.f) + log1pf(__expf(-fabsf(x)));       // stable softplus
        cnt = 1.f;
    }
#pragma unroll
    for (int m = 32; m > 0; m >>= 1) {
        sum += __shfl_xor(sum, m, 64);
        cnt += __shfl_xor(cnt, m, 64);
    }
    __shared__ float sS[4], sC[4];
    const int wave = threadIdx.x >> 6, lane = threadIdx.x & 63;
    if (lane == 0) { sS[wave] = sum; sC[wave] = cnt; }
    __syncthreads();
    if (threadIdx.x == 0) {
        unsafeAtomicAdd(&gstat[0], sS[0] + sS[1] + sS[2] + sS[3]);
        unsafeAtomicAdd(&gstat[1], sC[0] + sC[1] + sC[2] + sC[3]);
        __threadfence();
        unsigned t = atomicAdd((unsigned*)(gstat + 2), 1u);
        if (t == (unsigned)(gridDim.x - 1)) {
            float s2 = unsafeAtomicAdd(&gstat[0], 0.f);   // L2 reads
            float c2 = unsafeAtomicAdd(&gstat[1], 0.f);
            out[0] = s2 / fmaxf(c2, 1.f);
        }
    }
}

extern "C" void kernel_launch(void* const* d_in, const int* in_sizes, int n_in,
                              void* d_out, int out_size, void* d_ws, size_t ws_size,
                              hipStream_t stream) {
    const float* F = (const float*)d_in[0];
    const int* labels = (const int*)d_in[1];
    float* out = (float*)d_out;

    char* ws = (char*)d_ws;
    float4* corr = (float4*)ws;                       // 128 KB
    size_t off = (size_t)NROWS * 16;
    float2* partial = (float2*)(ws + off);            // 1 MB
    off += (size_t)JSPLIT * NROWS * 8;
    float* gstat = (float*)(ws + off);                // 16 B

    pairs_kernel<<<dim3(NROWS / 64, JSPLIT), 256, 0, stream>>>(
        F, labels, partial, corr, gstat);
    finalize_kernel<<<NROWS / 256, 256, 0, stream>>>(partial, corr, gstat, out);
}

// Round 11
// 125.840 us; speedup vs baseline: 1.2274x; 1.2274x over previous
//
#include <hip/hip_runtime.h>
#include <hip/hip_bf16.h>

// TripletLoss N=8192, D=128. Round 13: 32x32 MFMA main loop (ILP for trans).
// Round-10 post-mortem: prep-free staging moved prep's work into the hot
// loop x2 cost (pairs 104us); and total-minus-kernels ~= 46-55us at ANY
// dispatch count (2..5) -> fixed harness overhead, not per-launch. Lever is
// kernel time. Round-8's 49.5us pairs is ~40% utilized: the per-pair
// epilogue chain (fmax->sqrt->exp2->add/fma, 2 quarter-rate trans) has only
// 4 independent chains/wave at 16x16. Switch to mfma_f32_32x32x16_bf16:
// 16 independent chains/wave, LDS reads halve (8B/pair), jt overhead halves.
// Regs: a[8]=32 + x2ih=16 + nl/ns=32 + addr ~12 + acc16(AGPR) ~= 112 <= 128
// @ (256,4) -- no spill (tell: WRITE_SIZE). corr = proven label-scan head
// (by<8). 3 dispatches: prep, pairs, finalize.
// t-units: Fb,x2 pre-scaled by AK1=sqrt2*log2(e); acc = AK1^2*dot;
// C-init -(x2i+x2j)/2 scaled => acc = -AK1^2*d2/2; t=sqrt(-acc);
// exp(-dist)=exp2(-t); dist=t*ln2; pos=exp2(t+C2).

typedef __bf16 bf16x8 __attribute__((ext_vector_type(8)));
typedef float f32x16 __attribute__((ext_vector_type(16)));

#define NROWS 8192
#define DIM 128
#define JTILE 64
#define LDS_STRIDE 136    // 128+8 bf16 pad: 272B rows (17x16B, odd -> spread)
#define NLABELS 512
#define GCAP 64           // max rows/label (E=16; P(>64) ~ 1e-30)
#define JSPLIT 16
#define JSPAN (NROWS / JSPLIT)   // 512
#define JITERS (JSPAN / JTILE)   // 8
#define MARGIN_F 0.3f
#define AK1F 2.04027892f      // sqrt2 * log2(e)
#define AK1SQ 4.16273807f     // AK1^2
#define EPS_T 2.08137e-8f     // AK1^2 * 5e-9 (matches reference clip(d2,1e-8))
#define C2F (-43.2808512f)    // -30*log2(e)
#define LN2F 0.69314718f

// ---------------- kernel 1: scaled bf16 cast + row norms + zero gstat ------
__global__ __launch_bounds__(256) void prep_kernel(const float* __restrict__ F,
                                                   __hip_bfloat16* __restrict__ Fb,
                                                   float* __restrict__ x2,
                                                   float* __restrict__ gstat) {
    const int tid = threadIdx.x;
    const int wave = tid >> 6, lane = tid & 63;
    const int row = blockIdx.x * 4 + wave;
    float2 f = ((const float2*)(F + (size_t)row * DIM))[lane];
    f.x *= AK1F; f.y *= AK1F;
    ((__hip_bfloat162*)(Fb + (size_t)row * DIM))[lane] = __float22bfloat162_rn(f);
    float ss = f.x * f.x + f.y * f.y;
#pragma unroll
    for (int m = 32; m > 0; m >>= 1) ss += __shfl_xor(ss, m, 64);
    if (lane == 0) x2[row] = ss;
    if (blockIdx.x == 0 && tid < 4) gstat[tid] = 0.f;
}

// ---------------- kernel 2: 32x32-MFMA GEMM + mining; corr head on by<8 ----
// C/D layout (m74/m101): col = lane&31, row = (reg&3) + 8*(reg>>2) + 4*(lane>>5).
// A: row = lane&31, k = ki*16 + (lane>>5)*8 + [0,8). B: col = lane&31, same k.
template<bool DIAG>
__device__ __forceinline__ void tile_body(const __hip_bfloat16* __restrict__ sB,
                                          const float* __restrict__ sX2,
                                          const bf16x8 (&a)[8],
                                          const float (&x2ih)[16],
                                          float (&nl)[16], float (&ns)[16],
                                          int col, int hi, int d0) {
    const __hip_bfloat16* bp = sB + col * LDS_STRIDE + hi * 8;  // col includes jt*32
    const float xjh = sX2[col];                                 // -0.5*x2j
    f32x16 acc;
#pragma unroll
    for (int r = 0; r < 16; ++r) acc[r] = x2ih[r] + xjh;
#pragma unroll
    for (int ki = 0; ki < 8; ++ki) {
        bf16x8 b = *(const bf16x8*)(bp + ki * 16);
        acc = __builtin_amdgcn_mfma_f32_32x32x16_bf16(a[ki], b, acc, 0, 0, 0);
    }
#pragma unroll
    for (int r = 0; r < 16; ++r) {
        const int R = (r & 3) + 8 * (r >> 2);        // compile-time row offset
        float d2h = fmaxf(-acc[r], EPS_T);           // = AK1^2*d2/2, clipped
        float t = __builtin_amdgcn_sqrtf(d2h);       // dist = t*ln2
        float ne = __builtin_amdgcn_exp2f(-t);       // exp(-dist)
        if (DIAG) ne = (d0 == R) ? 0.f : ne;         // self-pair
        nl[r] += ne;
        ns[r] = fmaf(ne, t, ns[r]);
    }
}

__global__ __launch_bounds__(256, 4) void pairs_kernel(
        const __hip_bfloat16* __restrict__ Fb,
        const float* __restrict__ x2,
        const float* __restrict__ F,
        const int* __restrict__ labels,
        float2* __restrict__ partial,
        float4* __restrict__ corr) {
    __shared__ __hip_bfloat16 sB[JTILE * LDS_STRIDE];
    __shared__ float sX2[JTILE];     // -0.5 * x2j (t-units)
    __shared__ int sIdx[GCAP];
    __shared__ int sCnt;

    const int tid = threadIdx.x;
    const int bx = blockIdx.x, by = blockIdx.y;

    // ---- corr head: 512 blocks (by<8), one label each, before the j-loop --
    if (by < 8) {
        const int L = by * 64 + bx;
        if (tid == 0) sCnt = 0;
        __syncthreads();
        for (int it = 0; it < NROWS / 1024; ++it) {     // 8 iterations
            const int g = it * 1024 + tid * 4;
            int4 lv = *(const int4*)(labels + g);
#pragma unroll
            for (int k = 0; k < 4; ++k) {
                int lab = (k == 0) ? lv.x : (k == 1) ? lv.y : (k == 2) ? lv.z : lv.w;
                if (lab == L) {
                    int pos = atomicAdd(&sCnt, 1);
                    if (pos < GCAP) sIdx[pos] = g + k;
                }
            }
        }
        __syncthreads();
        const int gsz = sCnt < GCAP ? sCnt : GCAP;
        if (gsz > 0) {
            float* sAcc = (float*)sB;          // overlay, pre-staging
            float* plA = sAcc;
            float* psA = sAcc + GCAP;
            float* nlA = sAcc + 2 * GCAP;
            float* nsA = sAcc + 3 * GCAP;
            if (tid < GCAP) { plA[tid] = 0.f; psA[tid] = 0.f; nlA[tid] = 0.f; nsA[tid] = 0.f; }
            __syncthreads();
            const int npair = gsz * gsz;
            for (int p = tid; p < npair; p += 256) {
                const int aI = p / gsz, bI = p - aI * gsz;
                if (aI == bI) continue;
                const float4* pa = (const float4*)(F + (size_t)sIdx[aI] * DIM);
                const float4* pb = (const float4*)(F + (size_t)sIdx[bI] * DIM);
                float dot = 0.f, ssa = 0.f, ssb = 0.f;
#pragma unroll 8
                for (int u = 0; u < 32; ++u) {
                    float4 va = pa[u], vb = pb[u];
                    dot = fmaf(va.x, vb.x, fmaf(va.y, vb.y, fmaf(va.z, vb.z, fmaf(va.w, vb.w, dot))));
                    ssa = fmaf(va.x, va.x, fmaf(va.y, va.y, fmaf(va.z, va.z, fmaf(va.w, va.w, ssa))));
                    ssb = fmaf(vb.x, vb.x, fmaf(vb.y, vb.y, fmaf(vb.z, vb.z, fmaf(vb.w, vb.w, ssb))));
                }
                float d2h = fmaxf((0.5f * (ssa + ssb) - dot) * AK1SQ, EPS_T);
                float t = __builtin_amdgcn_sqrtf(d2h);
                float ne = __builtin_amdgcn_exp2f(-t);
                float pe = __builtin_amdgcn_exp2f(t + C2F);
                unsafeAtomicAdd(&nlA[aI], ne);
                unsafeAtomicAdd(&nsA[aI], ne * t);
                unsafeAtomicAdd(&plA[aI], pe);
                unsafeAtomicAdd(&psA[aI], pe * t);
            }
            __syncthreads();
            if (tid < gsz)
                corr[sIdx[tid]] = make_float4(plA[tid], psA[tid], -nlA[tid], -nsA[tid]);
        }
        __syncthreads();   // corr LDS use done before staging overwrites
    }

    // ---- main loop: 128 i-rows per block, 32 per wave (one 32-row group) --
    const int wave = tid >> 6;
    const int lane = tid & 63;
    const int col = lane & 31;     // A-row / B-col / C-col index
    const int hi = lane >> 5;      // k-half selector
    const int ibw = bx * 128 + wave * 32;

    bf16x8 a[8];
#pragma unroll
    for (int ki = 0; ki < 8; ++ki)
        a[ki] = *(const bf16x8*)(Fb + (size_t)(ibw + col) * DIM + ki * 16 + hi * 8);

    float x2ih[16];
#pragma unroll
    for (int r = 0; r < 16; ++r)
        x2ih[r] = -0.5f * x2[ibw + ((r & 3) + 8 * (r >> 2)) + 4 * hi];

    float nl[16], ns[16];
#pragma unroll
    for (int r = 0; r < 16; ++r) { nl[r] = 0.f; ns[r] = 0.f; }

    const int j0 = by * JSPAN;
    // block's 128 i-rows span global 64-j tiles 2*bx and 2*bx+1
    const int djb0 = 2 * bx - by * JITERS;

    for (int jb = 0; jb < JITERS; ++jb) {
        const int jbase = j0 + jb * JTILE;
        __syncthreads();   // previous tile's readers done
#pragma unroll
        for (int s = 0; s < 4; ++s) {
            int c = tid + s * 256;
            int jr = c >> 4, ck = c & 15;
            *(bf16x8*)(sB + jr * LDS_STRIDE + ck * 8) =
                *(const bf16x8*)(Fb + (size_t)(jbase + jr) * DIM + ck * 8);
        }
        if (tid < JTILE) sX2[tid] = -0.5f * x2[jbase + tid];
        __syncthreads();

        const bool diag = (unsigned)(jb - djb0) <= 1u;
#pragma unroll
        for (int jt = 0; jt < 2; ++jt) {
            const int jcol = jt * 32 + col;
            const int d0 = jbase + jcol - ibw - 4 * hi;   // self iff == R
            if (diag)
                tile_body<true >(sB, sX2, a, x2ih, nl, ns, jcol, hi, d0);
            else
                tile_body<false>(sB, sX2, a, x2ih, nl, ns, jcol, hi, d0);
        }
    }

    // row-sums: reduce over the 32 cols (lanes within each half-wave)
#pragma unroll
    for (int m = 1; m < 32; m <<= 1) {
#pragma unroll
        for (int r = 0; r < 16; ++r) {
            nl[r] += __shfl_xor(nl[r], m, 64);
            ns[r] += __shfl_xor(ns[r], m, 64);
        }
    }
    if (col == 0) {      // lanes 0 and 32 each write their 16 rows
#pragma unroll
        for (int r = 0; r < 16; ++r)
            partial[(size_t)by * NROWS + ibw + ((r & 3) + 8 * (r >> 2)) + 4 * hi] =
                make_float2(nl[r], ns[r]);
    }
}

// ---------------- kernel 3: per-row loss, reduce, final divide -------------
__global__ __launch_bounds__(256) void finalize_kernel(const float2* __restrict__ partial,
                                                       const float4* __restrict__ corr,
                                                       float* __restrict__ gstat,
                                                       float* __restrict__ out) {
    const int row = blockIdx.x * 256 + threadIdx.x;
    float4 c = corr[row];
    float nl = c.z, ns = c.w;    // negative corrections (subtract same-label mass)
#pragma unroll
    for (int s = 0; s < JSPLIT; ++s) {
        float2 p = partial[(size_t)s * NROWS + row];
        nl += p.x; ns += p.y;
    }
    float sum = 0.f, cnt = 0.f;
    if (c.x > 0.f && nl > 0.f) {
        float x = fmaf(LN2F, c.y / c.x - ns / nl, MARGIN_F);   // wp - wn + margin
        sum = fmaxf(x, 0.f) + log1pf(__expf(-fabsf(x)));       // stable softplus
        cnt = 1.f;
    }
#pragma unroll
    for (int m = 32; m > 0; m >>= 1) {
        sum += __shfl_xor(sum, m, 64);
        cnt += __shfl_xor(cnt, m, 64);
    }
    __shared__ float sS[4], sC[4];
    const int wave = threadIdx.x >> 6, lane = threadIdx.x & 63;
    if (lane == 0) { sS[wave] = sum; sC[wave] = cnt; }
    __syncthreads();
    if (threadIdx.x == 0) {
        unsafeAtomicAdd(&gstat[0], sS[0] + sS[1] + sS[2] + sS[3]);
        unsafeAtomicAdd(&gstat[1], sC[0] + sC[1] + sC[2] + sC[3]);
        __threadfence();
        unsigned t = atomicAdd((unsigned*)(gstat + 2), 1u);
        if (t == (unsigned)(gridDim.x - 1)) {
            float s2 = unsafeAtomicAdd(&gstat[0], 0.f);   // L2 reads
            float c2 = unsafeAtomicAdd(&gstat[1], 0.f);
            out[0] = s2 / fmaxf(c2, 1.f);
        }
    }
}

extern "C" void kernel_launch(void* const* d_in, const int* in_sizes, int n_in,
                              void* d_out, int out_size, void* d_ws, size_t ws_size,
                              hipStream_t stream) {
    const float* F = (const float*)d_in[0];
    const int* labels = (const int*)d_in[1];
    float* out = (float*)d_out;

    char* ws = (char*)d_ws;
    __hip_bfloat16* Fb = (__hip_bfloat16*)ws;                        // 2 MB
    size_t off = (size_t)NROWS * DIM * 2;
    float* x2 = (float*)(ws + off);    off += (size_t)NROWS * 4;     // 32 KB
    float4* corr = (float4*)(ws + off); off += (size_t)NROWS * 16;   // 128 KB
    float2* partial = (float2*)(ws + off);                           // 1 MB
    off += (size_t)JSPLIT * NROWS * 8;
    float* gstat = (float*)(ws + off);                               // 16 B

    prep_kernel<<<NROWS / 4, 256, 0, stream>>>(F, Fb, x2, gstat);
    pairs_kernel<<<dim3(NROWS / 128, JSPLIT), 256, 0, stream>>>(
        Fb, x2, F, labels, partial, corr);
    finalize_kernel<<<NROWS / 256, 256, 0, stream>>>(partial, corr, gstat, out);
}

// Round 12
// 119.058 us; speedup vs baseline: 1.2973x; 1.0570x over previous
//
#include <hip/hip_runtime.h>
#include <hip/hip_bf16.h>

// TripletLoss N=8192, D=128. Round 14: 32x32 MFMA + relaxed register cap.
// Round-13 post-mortem: 32x32 worked (bank conflicts 4.19M -> 0, absmax 0.0)
// but __launch_bounds__(256,4) caps arch VGPRs at 64 vs the ~92 needed
// (a[8]=32, nl/ns=32, x2ih=16, addr ~12, acc16 in AGPR) -> ~28-reg hot-loop
// spill, WRITE_SIZE 25MB, 72.8us. The per-SIMD pool is 512 regs (m69), and
// ~110 unified/wave naturally yields 4 waves/SIMD -- the cap was the ONLY
// thing forcing the spill. Single change this round: launch_bounds(256,2)
// (cap 256; compiler allocates what it needs, occupancy self-selects ~4
// waves/SIMD). Everything else frozen.
// t-units: Fb,x2 pre-scaled by AK1=sqrt2*log2(e); C-init -(x2i+x2j)/2 =>
// acc = -AK1^2*d2/2; t=sqrt(-acc); exp(-dist)=exp2(-t); dist=t*ln2;
// positives exp(dist-30)=exp2(t+C2).

typedef __bf16 bf16x8 __attribute__((ext_vector_type(8)));
typedef float f32x16 __attribute__((ext_vector_type(16)));

#define NROWS 8192
#define DIM 128
#define JTILE 64
#define LDS_STRIDE 136    // 128+8 bf16 pad: 272B rows (17x16B, odd -> spread)
#define NLABELS 512
#define GCAP 64           // max rows/label (E=16; P(>64) ~ 1e-30)
#define JSPLIT 16
#define JSPAN (NROWS / JSPLIT)   // 512
#define JITERS (JSPAN / JTILE)   // 8
#define MARGIN_F 0.3f
#define AK1F 2.04027892f      // sqrt2 * log2(e)
#define AK1SQ 4.16273807f     // AK1^2
#define EPS_T 2.08137e-8f     // AK1^2 * 5e-9 (matches reference clip(d2,1e-8))
#define C2F (-43.2808512f)    // -30*log2(e)
#define LN2F 0.69314718f

// ---------------- kernel 1: scaled bf16 cast + row norms + zero gstat ------
__global__ __launch_bounds__(256) void prep_kernel(const float* __restrict__ F,
                                                   __hip_bfloat16* __restrict__ Fb,
                                                   float* __restrict__ x2,
                                                   float* __restrict__ gstat) {
    const int tid = threadIdx.x;
    const int wave = tid >> 6, lane = tid & 63;
    const int row = blockIdx.x * 4 + wave;
    float2 f = ((const float2*)(F + (size_t)row * DIM))[lane];
    f.x *= AK1F; f.y *= AK1F;
    ((__hip_bfloat162*)(Fb + (size_t)row * DIM))[lane] = __float22bfloat162_rn(f);
    float ss = f.x * f.x + f.y * f.y;
#pragma unroll
    for (int m = 32; m > 0; m >>= 1) ss += __shfl_xor(ss, m, 64);
    if (lane == 0) x2[row] = ss;
    if (blockIdx.x == 0 && tid < 4) gstat[tid] = 0.f;
}

// ---------------- kernel 2: 32x32-MFMA GEMM + mining; corr head on by<8 ----
// C/D layout (m74/m101): col = lane&31, row = (reg&3) + 8*(reg>>2) + 4*(lane>>5).
// A: row = lane&31, k = ki*16 + (lane>>5)*8 + [0,8). B: col = lane&31, same k.
template<bool DIAG>
__device__ __forceinline__ void tile_body(const __hip_bfloat16* __restrict__ sB,
                                          const float* __restrict__ sX2,
                                          const bf16x8 (&a)[8],
                                          const float (&x2ih)[16],
                                          float (&nl)[16], float (&ns)[16],
                                          int col, int hi, int d0) {
    const __hip_bfloat16* bp = sB + col * LDS_STRIDE + hi * 8;  // col includes jt*32
    const float xjh = sX2[col];                                 // -0.5*x2j
    f32x16 acc;
#pragma unroll
    for (int r = 0; r < 16; ++r) acc[r] = x2ih[r] + xjh;
#pragma unroll
    for (int ki = 0; ki < 8; ++ki) {
        bf16x8 b = *(const bf16x8*)(bp + ki * 16);
        acc = __builtin_amdgcn_mfma_f32_32x32x16_bf16(a[ki], b, acc, 0, 0, 0);
    }
#pragma unroll
    for (int r = 0; r < 16; ++r) {
        const int R = (r & 3) + 8 * (r >> 2);        // compile-time row offset
        float d2h = fmaxf(-acc[r], EPS_T);           // = AK1^2*d2/2, clipped
        float t = __builtin_amdgcn_sqrtf(d2h);       // dist = t*ln2
        float ne = __builtin_amdgcn_exp2f(-t);       // exp(-dist)
        if (DIAG) ne = (d0 == R) ? 0.f : ne;         // self-pair
        nl[r] += ne;
        ns[r] = fmaf(ne, t, ns[r]);
    }
}

__global__ __launch_bounds__(256, 2) void pairs_kernel(
        const __hip_bfloat16* __restrict__ Fb,
        const float* __restrict__ x2,
        const float* __restrict__ F,
        const int* __restrict__ labels,
        float2* __restrict__ partial,
        float4* __restrict__ corr) {
    __shared__ __hip_bfloat16 sB[JTILE * LDS_STRIDE];
    __shared__ float sX2[JTILE];     // -0.5 * x2j (t-units)
    __shared__ int sIdx[GCAP];
    __shared__ int sCnt;

    const int tid = threadIdx.x;
    const int bx = blockIdx.x, by = blockIdx.y;

    // ---- corr head: 512 blocks (by<8), one label each, before the j-loop --
    if (by < 8) {
        const int L = by * 64 + bx;
        if (tid == 0) sCnt = 0;
        __syncthreads();
        for (int it = 0; it < NROWS / 1024; ++it) {     // 8 iterations
            const int g = it * 1024 + tid * 4;
            int4 lv = *(const int4*)(labels + g);
#pragma unroll
            for (int k = 0; k < 4; ++k) {
                int lab = (k == 0) ? lv.x : (k == 1) ? lv.y : (k == 2) ? lv.z : lv.w;
                if (lab == L) {
                    int pos = atomicAdd(&sCnt, 1);
                    if (pos < GCAP) sIdx[pos] = g + k;
                }
            }
        }
        __syncthreads();
        const int gsz = sCnt < GCAP ? sCnt : GCAP;
        if (gsz > 0) {
            float* sAcc = (float*)sB;          // overlay, pre-staging
            float* plA = sAcc;
            float* psA = sAcc + GCAP;
            float* nlA = sAcc + 2 * GCAP;
            float* nsA = sAcc + 3 * GCAP;
            if (tid < GCAP) { plA[tid] = 0.f; psA[tid] = 0.f; nlA[tid] = 0.f; nsA[tid] = 0.f; }
            __syncthreads();
            const int npair = gsz * gsz;
            for (int p = tid; p < npair; p += 256) {
                const int aI = p / gsz, bI = p - aI * gsz;
                if (aI == bI) continue;
                const float4* pa = (const float4*)(F + (size_t)sIdx[aI] * DIM);
                const float4* pb = (const float4*)(F + (size_t)sIdx[bI] * DIM);
                float dot = 0.f, ssa = 0.f, ssb = 0.f;
#pragma unroll 8
                for (int u = 0; u < 32; ++u) {
                    float4 va = pa[u], vb = pb[u];
                    dot = fmaf(va.x, vb.x, fmaf(va.y, vb.y, fmaf(va.z, vb.z, fmaf(va.w, vb.w, dot))));
                    ssa = fmaf(va.x, va.x, fmaf(va.y, va.y, fmaf(va.z, va.z, fmaf(va.w, va.w, ssa))));
                    ssb = fmaf(vb.x, vb.x, fmaf(vb.y, vb.y, fmaf(vb.z, vb.z, fmaf(vb.w, vb.w, ssb))));
                }
                float d2h = fmaxf((0.5f * (ssa + ssb) - dot) * AK1SQ, EPS_T);
                float t = __builtin_amdgcn_sqrtf(d2h);
                float ne = __builtin_amdgcn_exp2f(-t);
                float pe = __builtin_amdgcn_exp2f(t + C2F);
                unsafeAtomicAdd(&nlA[aI], ne);
                unsafeAtomicAdd(&nsA[aI], ne * t);
                unsafeAtomicAdd(&plA[aI], pe);
                unsafeAtomicAdd(&psA[aI], pe * t);
            }
            __syncthreads();
            if (tid < gsz)
                corr[sIdx[tid]] = make_float4(plA[tid], psA[tid], -nlA[tid], -nsA[tid]);
        }
        __syncthreads();   // corr LDS use done before staging overwrites
    }

    // ---- main loop: 128 i-rows per block, 32 per wave (one 32-row group) --
    const int wave = tid >> 6;
    const int lane = tid & 63;
    const int col = lane & 31;     // A-row / B-col / C-col index
    const int hi = lane >> 5;      // k-half selector
    const int ibw = bx * 128 + wave * 32;

    bf16x8 a[8];
#pragma unroll
    for (int ki = 0; ki < 8; ++ki)
        a[ki] = *(const bf16x8*)(Fb + (size_t)(ibw + col) * DIM + ki * 16 + hi * 8);

    float x2ih[16];
#pragma unroll
    for (int r = 0; r < 16; ++r)
        x2ih[r] = -0.5f * x2[ibw + ((r & 3) + 8 * (r >> 2)) + 4 * hi];

    float nl[16], ns[16];
#pragma unroll
    for (int r = 0; r < 16; ++r) { nl[r] = 0.f; ns[r] = 0.f; }

    const int j0 = by * JSPAN;
    // block's 128 i-rows span global 64-j tiles 2*bx and 2*bx+1
    const int djb0 = 2 * bx - by * JITERS;

    for (int jb = 0; jb < JITERS; ++jb) {
        const int jbase = j0 + jb * JTILE;
        __syncthreads();   // previous tile's readers done
#pragma unroll
        for (int s = 0; s < 4; ++s) {
            int c = tid + s * 256;
            int jr = c >> 4, ck = c & 15;
            *(bf16x8*)(sB + jr * LDS_STRIDE + ck * 8) =
                *(const bf16x8*)(Fb + (size_t)(jbase + jr) * DIM + ck * 8);
        }
        if (tid < JTILE) sX2[tid] = -0.5f * x2[jbase + tid];
        __syncthreads();

        const bool diag = (unsigned)(jb - djb0) <= 1u;
#pragma unroll
        for (int jt = 0; jt < 2; ++jt) {
            const int jcol = jt * 32 + col;
            const int d0 = jbase + jcol - ibw - 4 * hi;   // self iff == R
            if (diag)
                tile_body<true >(sB, sX2, a, x2ih, nl, ns, jcol, hi, d0);
            else
                tile_body<false>(sB, sX2, a, x2ih, nl, ns, jcol, hi, d0);
        }
    }

    // row-sums: reduce over the 32 cols (lanes within each half-wave)
#pragma unroll
    for (int m = 1; m < 32; m <<= 1) {
#pragma unroll
        for (int r = 0; r < 16; ++r) {
            nl[r] += __shfl_xor(nl[r], m, 64);
            ns[r] += __shfl_xor(ns[r], m, 64);
        }
    }
    if (col == 0) {      // lanes 0 and 32 each write their 16 rows
#pragma unroll
        for (int r = 0; r < 16; ++r)
            partial[(size_t)by * NROWS + ibw + ((r & 3) + 8 * (r >> 2)) + 4 * hi] =
                make_float2(nl[r], ns[r]);
    }
}

// ---------------- kernel 3: per-row loss, reduce, final divide -------------
__global__ __launch_bounds__(256) void finalize_kernel(const float2* __restrict__ partial,
                                                       const float4* __restrict__ corr,
                                                       float* __restrict__ gstat,
                                                       float* __restrict__ out) {
    const int row = blockIdx.x * 256 + threadIdx.x;
    float4 c = corr[row];
    float nl = c.z, ns = c.w;    // negative corrections (subtract same-label mass)
#pragma unroll
    for (int s = 0; s < JSPLIT; ++s) {
        float2 p = partial[(size_t)s * NROWS + row];
        nl += p.x; ns += p.y;
    }
    float sum = 0.f, cnt = 0.f;
    if (c.x > 0.f && nl > 0.f) {
        float x = fmaf(LN2F, c.y / c.x - ns / nl, MARGIN_F);   // wp - wn + margin
        sum = fmaxf(x, 0.f) + log1pf(__expf(-fabsf(x)));       // stable softplus
        cnt = 1.f;
    }
#pragma unroll
    for (int m = 32; m > 0; m >>= 1) {
        sum += __shfl_xor(sum, m, 64);
        cnt += __shfl_xor(cnt, m, 64);
    }
    __shared__ float sS[4], sC[4];
    const int wave = threadIdx.x >> 6, lane = threadIdx.x & 63;
    if (lane == 0) { sS[wave] = sum; sC[wave] = cnt; }
    __syncthreads();
    if (threadIdx.x == 0) {
        unsafeAtomicAdd(&gstat[0], sS[0] + sS[1] + sS[2] + sS[3]);
        unsafeAtomicAdd(&gstat[1], sC[0] + sC[1] + sC[2] + sC[3]);
        __threadfence();
        unsigned t = atomicAdd((unsigned*)(gstat + 2), 1u);
        if (t == (unsigned)(gridDim.x - 1)) {
            float s2 = unsafeAtomicAdd(&gstat[0], 0.f);   // L2 reads
            float c2 = unsafeAtomicAdd(&gstat[1], 0.f);
            out[0] = s2 / fmaxf(c2, 1.f);
        }
    }
}

extern "C" void kernel_launch(void* const* d_in, const int* in_sizes, int n_in,
                              void* d_out, int out_size, void* d_ws, size_t ws_size,
                              hipStream_t stream) {
    const float* F = (const float*)d_in[0];
    const int* labels = (const int*)d_in[1];
    float* out = (float*)d_out;

    char* ws = (char*)d_ws;
    __hip_bfloat16* Fb = (__hip_bfloat16*)ws;                        // 2 MB
    size_t off = (size_t)NROWS * DIM * 2;
    float* x2 = (float*)(ws + off);    off += (size_t)NROWS * 4;     // 32 KB
    float4* corr = (float4*)(ws + off); off += (size_t)NROWS * 16;   // 128 KB
    float2* partial = (float2*)(ws + off);                           // 1 MB
    off += (size_t)JSPLIT * NROWS * 8;
    float* gstat = (float*)(ws + off);                               // 16 B

    prep_kernel<<<NROWS / 4, 256, 0, stream>>>(F, Fb, x2, gstat);
    pairs_kernel<<<dim3(NROWS / 128, JSPLIT), 256, 0, stream>>>(
        Fb, x2, F, labels, partial, corr);
    finalize_kernel<<<NROWS / 256, 256, 0, stream>>>(partial, corr, gstat, out);
}